// Round 4
// baseline (168.016 us; speedup 1.0000x reference)
//
#include <hip/hip_runtime.h>
#include <hip/hip_bf16.h>

// QuantizedConv2d: B=8, Cin=Cout=320, H=W=64, K=3, stride=1, pad=1.
// out = scale[co] * conv_zp_padded_int8(x_int, W) + bias_eff[co]
// bias_eff[co] = bias[co] - scale[co]*zp*sum(W[co]); x padded with zp byte.

typedef int v4i __attribute__((ext_vector_type(4)));

#define B_   8
#define CIN  320
#define COUT 320
#define H_   64
#define W_   64
#define HW_  4096
#define HP   66
#define WP   66
#define XPAD_BYTES (B_*HP*WP*CIN)
#define W8_BYTES (COUT*9*CIN)

// ---------------------------------------------------------------------------
// Kernel 1: weight repack int32 [O][I][3][3] -> int8 [co][tap][ci], fused
// with per-channel effective bias (first 320 global threads).
__global__ __launch_bounds__(256) void repack_bias_kernel(const int* __restrict__ wint,
                                                          unsigned char* __restrict__ w8,
                                                          const float* __restrict__ wsum,
                                                          const float* __restrict__ scale,
                                                          const float* __restrict__ bias,
                                                          const float* __restrict__ zp_p,
                                                          float* __restrict__ be) {
    int j = blockIdx.x * 256 + threadIdx.x;     // < 230,400 dwords
    if (j < COUT) {
        float s = 0.f;
        #pragma unroll
        for (int tp = 0; tp < 9; ++tp) s += wsum[j*9 + tp];
        be[j] = bias[j] - scale[j] * zp_p[0] * s;
    }
    int co  = j / 720;
    int r   = j - co * 720;                     // tap*80 + d
    int tap = r / 80;
    int d   = r - tap * 80;
    int ci  = d * 4;
    const int* base = wint + (co * CIN + ci) * 9 + tap;
    unsigned b0 = (unsigned)(base[0]  & 0xFF);
    unsigned b1 = (unsigned)(base[9]  & 0xFF);
    unsigned b2 = (unsigned)(base[18] & 0xFF);
    unsigned b3 = (unsigned)(base[27] & 0xFF);
    ((unsigned*)w8)[j] = b0 | (b1 << 8) | (b2 << 16) | (b3 << 24);
}

// ---------------------------------------------------------------------------
// Kernel 2: quantize + pad (register transpose; LDS dword writes stride 81).
__global__ __launch_bounds__(256) void quant_pad_kernel(const float* __restrict__ x,
                                                        unsigned char* __restrict__ xpad,
                                                        const float* __restrict__ inv_p,
                                                        const float* __restrict__ zp_p) {
    __shared__ __align__(16) unsigned lds[64 * 81];
    int bid = blockIdx.x;
    int b  = bid / HP;
    int ph = bid - b * HP;
    int t  = threadIdx.x;
    float inv = inv_p[0];
    float zp  = zp_p[0];
    int zpi = (int)rintf(zp);
    unsigned zd = ((unsigned)(zpi & 0xFF)) * 0x01010101u;

    unsigned* rowbase = (unsigned*)(xpad + (size_t)((b * HP + ph) * WP) * CIN);

    if (ph == 0 || ph == HP - 1) {
        for (int j = t; j < WP * CIN / 4; j += 256) rowbase[j] = zd;
        return;
    }
    int h = ph - 1;
    const float* xrow = x + (size_t)b * CIN * H_ * W_ + h * W_;
    int wq = t & 15;
    int cg = t >> 4;
    #pragma unroll
    for (int i = 0; i < 5; ++i) {
        int ci0 = i * 64 + cg * 4;
        float4 f[4];
        #pragma unroll
        for (int jj = 0; jj < 4; ++jj)
            f[jj] = *(const float4*)(xrow + (size_t)(ci0 + jj) * HW_ + wq * 4);
        #pragma unroll
        for (int k = 0; k < 4; ++k) {
            unsigned d = 0;
            #pragma unroll
            for (int jj = 0; jj < 4; ++jj) {
                float v = (&f[jj].x)[k];
                float q = rintf(v * inv) + zp;
                q = fminf(fmaxf(q, -128.0f), 127.0f);
                int qi = (int)q;
                d |= ((unsigned)(qi & 0xFF)) << (8 * jj);
            }
            lds[(wq * 4 + k) * 81 + (ci0 >> 2)] = d;
        }
    }
    __syncthreads();
    if (t < 80)            rowbase[t] = zd;
    else if (t < 160)      rowbase[65 * 80 + (t - 80)] = zd;
    for (int j = t; j < 64 * 80; j += 256) {
        int p = j / 80;
        int d = j - p * 80;
        rowbase[80 + j] = lds[p * 81 + d];
    }
}

// ---------------------------------------------------------------------------
// Kernel 3: implicit-GEMM conv, BARRIER-FREE. C[32768][320] = A x B.
// Single-wave blocks (64 threads). Wave tile 64(M) x 80(N) = acc[4][5].
// Both A and B fragments load DIRECTLY from global (L1/L2) into registers:
//  - A frag: rows = pixels (NHWC xpad, 320 B apart), lanes (colc,q) read
//    16 x 64 B fully-consumed segments per load.
//  - B frag: w8 is already MFMA B-layout; contiguous 1 KB per load.
// No LDS, no __syncthreads -> compiler emits fine-grained vmcnt(N) and
// software-pipelines loads over MFMAs freely (AITER-style K-loop).
// Grid 512(M) x 4(N): A-sharing blocks differ by 512 (same XCD); B (921 KB)
// fits every XCD's L2; per-tap B slice (25 KB) fits L1.
__global__ __launch_bounds__(64) void conv_gemm_kernel(const unsigned char* __restrict__ xpad,
                                                       const unsigned char* __restrict__ w8,
                                                       const float* __restrict__ scale,
                                                       const float* __restrict__ be,
                                                       float* __restrict__ out) {
    int lane = threadIdx.x;
    int colc = lane & 15;
    int q    = lane >> 4;
    int m0   = blockIdx.x * 64;
    int n0   = blockIdx.y * 80;

    // A row pointers: one per mi (16-pixel group), at tap (0,0), byte q*16.
    const unsigned char* ap[4];
    #pragma unroll
    for (int mi = 0; mi < 4; ++mi) {
        int pix = m0 + mi * 16 + colc;
        int bb  = pix >> 12;
        int hw  = pix & 4095;
        ap[mi] = xpad + (size_t)(((bb * HP + (hw >> 6)) * WP + (hw & 63)) * CIN) + q * 16;
    }
    // B pointers: one per ni (16-cout group), tap 0, byte q*16.
    const unsigned char* bp[5];
    #pragma unroll
    for (int ni = 0; ni < 5; ++ni) {
        int co = n0 + ni * 16 + colc;
        bp[ni] = w8 + (size_t)co * (9 * CIN) + q * 16;
    }

    v4i acc[4][5];
    v4i zero = {0, 0, 0, 0};
    #pragma unroll
    for (int mi = 0; mi < 4; ++mi)
        #pragma unroll
        for (int ni = 0; ni < 5; ++ni) acc[mi][ni] = zero;

    #pragma unroll 1
    for (int kh = 0; kh < 3; ++kh) {
        // All offsets below are compile-time immediates (max 2*320+4*64 = 896).
        #pragma unroll
        for (int kw = 0; kw < 3; ++kw) {
            #pragma unroll
            for (int c5 = 0; c5 < 5; ++c5) {
                int off = kw * CIN + c5 * 64;
                v4i a[4], b[5];
                #pragma unroll
                for (int mi = 0; mi < 4; ++mi)
                    a[mi] = *(const v4i*)(ap[mi] + off);
                #pragma unroll
                for (int ni = 0; ni < 5; ++ni)
                    b[ni] = *(const v4i*)(bp[ni] + off);
                #pragma unroll
                for (int mi = 0; mi < 4; ++mi)
                    #pragma unroll
                    for (int ni = 0; ni < 5; ++ni)
                        acc[mi][ni] = __builtin_amdgcn_mfma_i32_16x16x64_i8(a[mi], b[ni], acc[mi][ni], 0, 0, 0);
            }
        }
        // advance one kh row: A by WP*CIN, B by 3 taps * CIN.
        #pragma unroll
        for (int mi = 0; mi < 4; ++mi) ap[mi] += WP * CIN;
        #pragma unroll
        for (int ni = 0; ni < 5; ++ni) bp[ni] += 3 * CIN;
    }

    // Epilogue: C/D layout col = lane&15 (co), row = q*4 + reg (pixel).
    #pragma unroll
    for (int ni = 0; ni < 5; ++ni) {
        int co = n0 + ni * 16 + colc;
        float s  = scale[co];
        float bz = be[co];
        #pragma unroll
        for (int mi = 0; mi < 4; ++mi) {
            int pix = m0 + mi * 16 + q * 4;
            int bb2 = pix >> 12;
            int hw  = pix & 4095;
            v4i v = acc[mi][ni];
            float4 o;
            o.x = s * (float)v.x + bz;
            o.y = s * (float)v.y + bz;
            o.z = s * (float)v.z + bz;
            o.w = s * (float)v.w + bz;
            *(float4*)(out + (size_t)(bb2 * COUT + co) * HW_ + hw) = o;
        }
    }
}

// ---------------------------------------------------------------------------
extern "C" void kernel_launch(void* const* d_in, const int* in_sizes, int n_in,
                              void* d_out, int out_size, void* d_ws, size_t ws_size,
                              hipStream_t stream) {
    const float* x     = (const float*)d_in[0];
    const int*   wint  = (const int*)d_in[1];
    const float* wsum  = (const float*)d_in[2];
    const float* scale = (const float*)d_in[3];
    const float* inv_p = (const float*)d_in[4];
    const float* zp_p  = (const float*)d_in[5];
    const float* bias  = (const float*)d_in[6];
    float* out = (float*)d_out;

    unsigned char* xpad = (unsigned char*)d_ws;
    unsigned char* w8   = xpad + XPAD_BYTES;
    float*         be   = (float*)(w8 + W8_BYTES);

    repack_bias_kernel<<<(COUT * 720) / 256, 256, 0, stream>>>(wint, w8, wsum, scale, bias, zp_p, be);
    quant_pad_kernel<<<B_ * HP, 256, 0, stream>>>(x, xpad, inv_p, zp_p);

    dim3 grid((B_ * H_ * W_) / 64, COUT / 80);        // 512 x 4, M fastest
    conv_gemm_kernel<<<grid, 64, 0, stream>>>(xpad, w8, scale, be, out);
}

// Round 5
// 165.933 us; speedup vs baseline: 1.0126x; 1.0126x over previous
//
#include <hip/hip_runtime.h>
#include <hip/hip_bf16.h>

// QuantizedConv2d: B=8, Cin=Cout=320, H=W=64, K=3, stride=1, pad=1.
// out = scale[co] * conv_zp_padded_int8(x_int, W) + bias_eff[co]
// bias_eff[co] = bias[co] - scale[co]*zp*sum(W[co]); x padded with zp byte.

typedef int v4i __attribute__((ext_vector_type(4)));

#define B_   8
#define CIN  320
#define COUT 320
#define H_   64
#define W_   64
#define HW_  4096
#define HP   66
#define WP   66
#define XPAD_BYTES (B_*HP*WP*CIN)
#define W8_BYTES (COUT*9*CIN)

// ---------------------------------------------------------------------------
// Kernel 1: weight repack int32 [O][I][3][3] -> int8 [co][tap][ci], fused
// with per-channel effective bias (first 320 global threads).
__global__ __launch_bounds__(256) void repack_bias_kernel(const int* __restrict__ wint,
                                                          unsigned char* __restrict__ w8,
                                                          const float* __restrict__ wsum,
                                                          const float* __restrict__ scale,
                                                          const float* __restrict__ bias,
                                                          const float* __restrict__ zp_p,
                                                          float* __restrict__ be) {
    int j = blockIdx.x * 256 + threadIdx.x;     // < 230,400 dwords
    if (j < COUT) {
        float s = 0.f;
        #pragma unroll
        for (int tp = 0; tp < 9; ++tp) s += wsum[j*9 + tp];
        be[j] = bias[j] - scale[j] * zp_p[0] * s;
    }
    int co  = j / 720;
    int r   = j - co * 720;                     // tap*80 + d
    int tap = r / 80;
    int d   = r - tap * 80;
    int ci  = d * 4;
    const int* base = wint + (co * CIN + ci) * 9 + tap;
    unsigned b0 = (unsigned)(base[0]  & 0xFF);
    unsigned b1 = (unsigned)(base[9]  & 0xFF);
    unsigned b2 = (unsigned)(base[18] & 0xFF);
    unsigned b3 = (unsigned)(base[27] & 0xFF);
    ((unsigned*)w8)[j] = b0 | (b1 << 8) | (b2 << 16) | (b3 << 24);
}

// ---------------------------------------------------------------------------
// Kernel 2: quantize + pad (register transpose; LDS dword writes stride 81).
__global__ __launch_bounds__(256) void quant_pad_kernel(const float* __restrict__ x,
                                                        unsigned char* __restrict__ xpad,
                                                        const float* __restrict__ inv_p,
                                                        const float* __restrict__ zp_p) {
    __shared__ __align__(16) unsigned lds[64 * 81];
    int bid = blockIdx.x;
    int b  = bid / HP;
    int ph = bid - b * HP;
    int t  = threadIdx.x;
    float inv = inv_p[0];
    float zp  = zp_p[0];
    int zpi = (int)rintf(zp);
    unsigned zd = ((unsigned)(zpi & 0xFF)) * 0x01010101u;

    unsigned* rowbase = (unsigned*)(xpad + (size_t)((b * HP + ph) * WP) * CIN);

    if (ph == 0 || ph == HP - 1) {
        for (int j = t; j < WP * CIN / 4; j += 256) rowbase[j] = zd;
        return;
    }
    int h = ph - 1;
    const float* xrow = x + (size_t)b * CIN * H_ * W_ + h * W_;
    int wq = t & 15;
    int cg = t >> 4;
    #pragma unroll
    for (int i = 0; i < 5; ++i) {
        int ci0 = i * 64 + cg * 4;
        float4 f[4];
        #pragma unroll
        for (int jj = 0; jj < 4; ++jj)
            f[jj] = *(const float4*)(xrow + (size_t)(ci0 + jj) * HW_ + wq * 4);
        #pragma unroll
        for (int k = 0; k < 4; ++k) {
            unsigned d = 0;
            #pragma unroll
            for (int jj = 0; jj < 4; ++jj) {
                float v = (&f[jj].x)[k];
                float q = rintf(v * inv) + zp;
                q = fminf(fmaxf(q, -128.0f), 127.0f);
                int qi = (int)q;
                d |= ((unsigned)(qi & 0xFF)) << (8 * jj);
            }
            lds[(wq * 4 + k) * 81 + (ci0 >> 2)] = d;
        }
    }
    __syncthreads();
    if (t < 80)            rowbase[t] = zd;
    else if (t < 160)      rowbase[65 * 80 + (t - 80)] = zd;
    for (int j = t; j < 64 * 80; j += 256) {
        int p = j / 80;
        int d = j - p * 80;
        rowbase[80 + j] = lds[p * 81 + d];
    }
}

// ---------------------------------------------------------------------------
// Kernel 3: implicit-GEMM conv, barrier-free + REGISTER DOUBLE-BUFFER.
// Single-wave blocks. Wave tile 64(M) x 80(N) = acc[4][5] (80 VGPR).
// Per chunk: issue chunk i+1's 9 global_load_dwordx4 into the alternate
// 36-reg buffer, then run chunk i's 20 MFMAs -> compiler emits
// s_waitcnt vmcnt(9) (never 0); L2 latency hidden behind the MFMA pipe.
// All 45 chunks fully unrolled; within a kh row the 15 chunk offsets are
// contiguous immediates 0..896 (taps along kw are adjacent in NHWC xpad,
// and w8 rows are contiguous); pointers bump only at the 2 kh boundaries.
__global__ __launch_bounds__(64, 2) void conv_gemm_kernel(const unsigned char* __restrict__ xpad,
                                                          const unsigned char* __restrict__ w8,
                                                          const float* __restrict__ scale,
                                                          const float* __restrict__ be,
                                                          float* __restrict__ out) {
    int lane = threadIdx.x;
    int colc = lane & 15;
    int q    = lane >> 4;
    int m0   = blockIdx.x * 64;
    int n0   = blockIdx.y * 80;

    // A row pointers: one per mi (16-pixel group), at tap (0,0), byte q*16.
    const unsigned char* ap[4];
    #pragma unroll
    for (int mi = 0; mi < 4; ++mi) {
        int pix = m0 + mi * 16 + colc;
        int bb  = pix >> 12;
        int hw  = pix & 4095;
        ap[mi] = xpad + (size_t)(((bb * HP + (hw >> 6)) * WP + (hw & 63)) * CIN) + q * 16;
    }
    // B pointers: one per ni (16-cout group), tap 0, byte q*16.
    const unsigned char* bp[5];
    #pragma unroll
    for (int ni = 0; ni < 5; ++ni) {
        int co = n0 + ni * 16 + colc;
        bp[ni] = w8 + (size_t)co * (9 * CIN) + q * 16;
    }

    v4i acc[4][5];
    v4i zero = {0, 0, 0, 0};
    #pragma unroll
    for (int mi = 0; mi < 4; ++mi)
        #pragma unroll
        for (int ni = 0; ni < 5; ++ni) acc[mi][ni] = zero;

    // Register double-buffer: fa/fb[2] (36 VGPRs each).
    v4i fa[2][4], fb[2][5];
    #pragma unroll
    for (int mi = 0; mi < 4; ++mi) fa[0][mi] = *(const v4i*)(ap[mi]);
    #pragma unroll
    for (int ni = 0; ni < 5; ++ni) fb[0][ni] = *(const v4i*)(bp[ni]);

    #pragma unroll
    for (int kh = 0; kh < 3; ++kh) {
        #pragma unroll
        for (int i = 0; i < 15; ++i) {
            const int cur = (kh * 15 + i) & 1;
            const int nxt = cur ^ 1;
            if (i < 14) {
                #pragma unroll
                for (int mi = 0; mi < 4; ++mi)
                    fa[nxt][mi] = *(const v4i*)(ap[mi] + (i + 1) * 64);
                #pragma unroll
                for (int ni = 0; ni < 5; ++ni)
                    fb[nxt][ni] = *(const v4i*)(bp[ni] + (i + 1) * 64);
            } else if (kh < 2) {
                // bump to next kh row, prefetch its chunk 0
                #pragma unroll
                for (int mi = 0; mi < 4; ++mi) ap[mi] += WP * CIN;
                #pragma unroll
                for (int ni = 0; ni < 5; ++ni) bp[ni] += 3 * CIN;
                #pragma unroll
                for (int mi = 0; mi < 4; ++mi) fa[nxt][mi] = *(const v4i*)(ap[mi]);
                #pragma unroll
                for (int ni = 0; ni < 5; ++ni) fb[nxt][ni] = *(const v4i*)(bp[ni]);
            }
            #pragma unroll
            for (int mi = 0; mi < 4; ++mi)
                #pragma unroll
                for (int ni = 0; ni < 5; ++ni)
                    acc[mi][ni] = __builtin_amdgcn_mfma_i32_16x16x64_i8(fa[cur][mi], fb[cur][ni], acc[mi][ni], 0, 0, 0);
        }
    }

    // Epilogue: C/D layout col = lane&15 (co), row = q*4 + reg (pixel).
    #pragma unroll
    for (int ni = 0; ni < 5; ++ni) {
        int co = n0 + ni * 16 + colc;
        float s  = scale[co];
        float bz = be[co];
        #pragma unroll
        for (int mi = 0; mi < 4; ++mi) {
            int pix = m0 + mi * 16 + q * 4;
            int bb2 = pix >> 12;
            int hw  = pix & 4095;
            v4i v = acc[mi][ni];
            float4 o;
            o.x = s * (float)v.x + bz;
            o.y = s * (float)v.y + bz;
            o.z = s * (float)v.z + bz;
            o.w = s * (float)v.w + bz;
            *(float4*)(out + (size_t)(bb2 * COUT + co) * HW_ + hw) = o;
        }
    }
}

// ---------------------------------------------------------------------------
extern "C" void kernel_launch(void* const* d_in, const int* in_sizes, int n_in,
                              void* d_out, int out_size, void* d_ws, size_t ws_size,
                              hipStream_t stream) {
    const float* x     = (const float*)d_in[0];
    const int*   wint  = (const int*)d_in[1];
    const float* wsum  = (const float*)d_in[2];
    const float* scale = (const float*)d_in[3];
    const float* inv_p = (const float*)d_in[4];
    const float* zp_p  = (const float*)d_in[5];
    const float* bias  = (const float*)d_in[6];
    float* out = (float*)d_out;

    unsigned char* xpad = (unsigned char*)d_ws;
    unsigned char* w8   = xpad + XPAD_BYTES;
    float*         be   = (float*)(w8 + W8_BYTES);

    repack_bias_kernel<<<(COUT * 720) / 256, 256, 0, stream>>>(wint, w8, wsum, scale, bias, zp_p, be);
    quant_pad_kernel<<<B_ * HP, 256, 0, stream>>>(x, xpad, inv_p, zp_p);

    dim3 grid((B_ * H_ * W_) / 64, COUT / 80);        // 512 x 4, M fastest
    conv_gemm_kernel<<<grid, 64, 0, stream>>>(xpad, w8, scale, be, out);
}